// Round 2
// baseline (408.117 us; speedup 1.0000x reference)
//
#include <hip/hip_runtime.h>
#include <math.h>

#define NB 64
#define NT 1024
#define NE 512
#define NR 1024
#define NA 128
#define NF 32
#define NK 31
#define CPAD 15
#define BN_EPS 1e-5f
#define TILE_T 32

// ---------------- q = query @ Wq : [B,A] ----------------
__global__ __launch_bounds__(128) void kq(const float* __restrict__ query,
                                          const float* __restrict__ Wq,
                                          float* __restrict__ qout) {
  __shared__ float qs[NR];
  int b = blockIdx.x;
  for (int i = threadIdx.x; i < NR; i += 128) qs[i] = query[b * NR + i];
  __syncthreads();
  int a = threadIdx.x;
  float acc = 0.f;
#pragma unroll 8
  for (int r = 0; r < NR; ++r) acc += qs[r] * Wq[r * NA + a];
  qout[b * NA + a] = acc;
}

// ------- energies[b,t] = tanh(q + key@Wk + loc(conv/bn/Wloc)) . v -------
__global__ __launch_bounds__(256) void ke(
    const float* __restrict__ key, const float* __restrict__ aw,
    const float* __restrict__ conv_w,
    const float* __restrict__ bn_g, const float* __restrict__ bn_b,
    const float* __restrict__ bn_m, const float* __restrict__ bn_v,
    const float* __restrict__ Wk, const float* __restrict__ Wloc,
    const float* __restrict__ vvec, const float* __restrict__ qproj,
    float* __restrict__ energies) {
  __shared__ float wk_lds[64 * 128];            // 32 KB: Wk e-chunk [64][128]
  __shared__ float key_lds[TILE_T * 68];        // key chunk [32][64], stride 68 (16B-aligned, conflict-free)
  __shared__ float feats[NF * 33];              // bn(relu(conv)) [f][t_local]
  __shared__ float x_lds[2][TILE_T + 2 * CPAD]; // conv input slice
  __shared__ float q_lds[NA];
  __shared__ float v_lds[NA];

  const int b = blockIdx.x;
  const int t0 = blockIdx.y * TILE_T;
  const int tid = threadIdx.x;
  const int tx = tid & 15;   // a-group
  const int ty = tid >> 4;   // owns t_local = ty*2 + {0,1}

  // stage conv input with zero padding
  if (tid < 2 * (TILE_T + 2 * CPAD)) {
    int c = tid / (TILE_T + 2 * CPAD);
    int i = tid - c * (TILE_T + 2 * CPAD);
    int t = t0 - CPAD + i;
    x_lds[c][i] = (t >= 0 && t < NT) ? aw[b * 2 * NT + c * NT + t] : 0.f;
  }
  if (tid < NA) {
    q_lds[tid] = qproj[b * NA + tid];
    v_lds[tid] = vvec[tid];
  }
  __syncthreads();

  // conv1d -> relu -> batchnorm(eval) into feats[f][tl]
  {
    int f = tid >> 3;
    int tl0 = (tid & 7) * 4;
    float scale = rsqrtf(bn_v[f] + BN_EPS) * bn_g[f];
    float bias = bn_b[f] - bn_m[f] * scale;
    for (int j = 0; j < 4; ++j) {
      int tl = tl0 + j;
      float acc = 0.f;
#pragma unroll
      for (int c = 0; c < 2; ++c) {
#pragma unroll
        for (int k = 0; k < NK; ++k)
          acc += conv_w[(f * 2 + c) * NK + k] * x_lds[c][tl + k];
      }
      acc = fmaxf(acc, 0.f);
      feats[f * 33 + tl] = acc * scale + bias;
    }
  }

  float acc[2][8];
#pragma unroll
  for (int i = 0; i < 2; ++i)
#pragma unroll
    for (int j = 0; j < 8; ++j) acc[i][j] = 0.f;

  const size_t keybase = (size_t)b * NT * NE + (size_t)t0 * NE;

  // GEMM: key[t0:t0+32, :] @ Wk  accumulated over 8 e-chunks of 64
  for (int ec = 0; ec < NE; ec += 64) {
    __syncthreads();
    // stage Wk chunk [64][128] — linear float4, conflict-free
#pragma unroll
    for (int p = 0; p < 8; ++p) {
      int idx = p * 1024 + tid * 4;
      *(float4*)&wk_lds[idx] = *(const float4*)&Wk[ec * NA + idx];
    }
    // stage key chunk [32][64]
    {
      int tl = tid >> 3;
      int e8 = (tid & 7) * 8;
      const float* src = &key[keybase + (size_t)tl * NE + ec + e8];
      *(float4*)&key_lds[tl * 68 + e8] = *(const float4*)src;
      *(float4*)&key_lds[tl * 68 + e8 + 4] = *(const float4*)(src + 4);
    }
    __syncthreads();
#pragma unroll 4
    for (int el = 0; el < 64; ++el) {
      float k0 = key_lds[(ty * 2 + 0) * 68 + el];
      float k1 = key_lds[(ty * 2 + 1) * 68 + el];
      float4 w0 = *(float4*)&wk_lds[el * 128 + tx * 4];
      float4 w1 = *(float4*)&wk_lds[el * 128 + 64 + tx * 4];
      acc[0][0] += k0 * w0.x; acc[0][1] += k0 * w0.y;
      acc[0][2] += k0 * w0.z; acc[0][3] += k0 * w0.w;
      acc[0][4] += k0 * w1.x; acc[0][5] += k0 * w1.y;
      acc[0][6] += k0 * w1.z; acc[0][7] += k0 * w1.w;
      acc[1][0] += k1 * w0.x; acc[1][1] += k1 * w0.y;
      acc[1][2] += k1 * w0.z; acc[1][3] += k1 * w0.w;
      acc[1][4] += k1 * w1.x; acc[1][5] += k1 * w1.y;
      acc[1][6] += k1 * w1.z; acc[1][7] += k1 * w1.w;
    }
  }

  // loc contribution: feats[f][t] @ Wloc[f][a]
#pragma unroll 4
  for (int f = 0; f < NF; ++f) {
    float f0 = feats[f * 33 + ty * 2 + 0];
    float f1 = feats[f * 33 + ty * 2 + 1];
    float4 w0 = *(const float4*)&Wloc[f * NA + tx * 4];
    float4 w1 = *(const float4*)&Wloc[f * NA + 64 + tx * 4];
    acc[0][0] += f0 * w0.x; acc[0][1] += f0 * w0.y;
    acc[0][2] += f0 * w0.z; acc[0][3] += f0 * w0.w;
    acc[0][4] += f0 * w1.x; acc[0][5] += f0 * w1.y;
    acc[0][6] += f0 * w1.z; acc[0][7] += f0 * w1.w;
    acc[1][0] += f1 * w0.x; acc[1][1] += f1 * w0.y;
    acc[1][2] += f1 * w0.z; acc[1][3] += f1 * w0.w;
    acc[1][4] += f1 * w1.x; acc[1][5] += f1 * w1.y;
    acc[1][6] += f1 * w1.z; acc[1][7] += f1 * w1.w;
  }

  // energies: tanh(q + acc) . v, reduced over the 16 tx lanes (width-16 shfl)
#pragma unroll
  for (int i = 0; i < 2; ++i) {
    float s = 0.f;
#pragma unroll
    for (int j = 0; j < 8; ++j) {
      int a = (j < 4) ? (tx * 4 + j) : (64 + tx * 4 + (j - 4));
      s += tanhf(q_lds[a] + acc[i][j]) * v_lds[a];
    }
    s += __shfl_xor(s, 1, 16);
    s += __shfl_xor(s, 2, 16);
    s += __shfl_xor(s, 4, 16);
    s += __shfl_xor(s, 8, 16);
    if (tx == 0) energies[b * NT + t0 + ty * 2 + i] = s;
  }
}

// ---------------- masked softmax over T ----------------
__global__ __launch_bounds__(256) void ks(const float* __restrict__ energies,
                                          const int* __restrict__ mask,
                                          float* __restrict__ wout) {
  __shared__ float redmax[4];
  __shared__ float redsum[4];
  int b = blockIdx.x;
  int tid = threadIdx.x;
  float vals[4];
  float mx = -INFINITY;
#pragma unroll
  for (int j = 0; j < 4; ++j) {
    int t = tid + j * 256;
    float e = energies[b * NT + t];
    if (mask[b * NT + t] != 0) e = -INFINITY;
    vals[j] = e;
    mx = fmaxf(mx, e);
  }
#pragma unroll
  for (int m = 1; m < 64; m <<= 1) mx = fmaxf(mx, __shfl_xor(mx, m, 64));
  if ((tid & 63) == 0) redmax[tid >> 6] = mx;
  __syncthreads();
  mx = fmaxf(fmaxf(redmax[0], redmax[1]), fmaxf(redmax[2], redmax[3]));
  float s = 0.f;
#pragma unroll
  for (int j = 0; j < 4; ++j) {
    float p = expf(vals[j] - mx);  // exp(-inf - mx) = 0 handles masked lanes
    vals[j] = p;
    s += p;
  }
#pragma unroll
  for (int m = 1; m < 64; m <<= 1) s += __shfl_xor(s, m, 64);
  if ((tid & 63) == 0) redsum[tid >> 6] = s;
  __syncthreads();
  s = redsum[0] + redsum[1] + redsum[2] + redsum[3];
  float inv = 1.f / s;
#pragma unroll
  for (int j = 0; j < 4; ++j) wout[b * NT + tid + j * 256] = vals[j] * inv;
}

// ---------------- context[b,e] = sum_t w[b,t] * key[b,t,e] ----------------
__global__ __launch_bounds__(256) void kc(const float* __restrict__ key,
                                          const float* __restrict__ w,
                                          float* __restrict__ ctx) {
  __shared__ float w_lds[NT];
  __shared__ float part[128];
  int b = blockIdx.x;
  int e0 = blockIdx.y * 128;
  int tid = threadIdx.x;
  for (int i = tid; i < NT; i += 256) w_lds[i] = w[b * NT + i];
  __syncthreads();
  int el = tid & 127;
  int th = tid >> 7;  // two t-halves
  const float* kp = key + (size_t)b * NT * NE + (size_t)th * 512 * NE + e0 + el;
  float acc = 0.f;
#pragma unroll 8
  for (int t = 0; t < 512; ++t) acc += w_lds[th * 512 + t] * kp[(size_t)t * NE];
  if (th == 1) part[el] = acc;
  __syncthreads();
  if (th == 0) ctx[b * NE + e0 + el] = acc + part[el];
}

extern "C" void kernel_launch(void* const* d_in, const int* in_sizes, int n_in,
                              void* d_out, int out_size, void* d_ws, size_t ws_size,
                              hipStream_t stream) {
  const float* query  = (const float*)d_in[0];
  const float* key    = (const float*)d_in[1];
  const float* aw     = (const float*)d_in[2];
  const int*   mask   = (const int*)d_in[3];
  const float* Wq     = (const float*)d_in[4];
  const float* Wk     = (const float*)d_in[5];
  const float* conv_w = (const float*)d_in[6];
  const float* bn_g   = (const float*)d_in[7];
  const float* bn_b   = (const float*)d_in[8];
  const float* bn_m   = (const float*)d_in[9];
  const float* bn_v   = (const float*)d_in[10];
  const float* Wloc   = (const float*)d_in[11];
  const float* vvec   = (const float*)d_in[12];

  float* ctx   = (float*)d_out;               // [B,E] = 32768
  float* wout  = (float*)d_out + NB * NE;     // [B,T] = 65536
  float* qproj = (float*)d_ws;                // [B,A]
  float* energies = (float*)d_ws + NB * NA;   // [B,T]

  kq<<<dim3(NB), dim3(128), 0, stream>>>(query, Wq, qproj);
  ke<<<dim3(NB, NT / TILE_T), dim3(256), 0, stream>>>(
      key, aw, conv_w, bn_g, bn_b, bn_m, bn_v, Wk, Wloc, vvec, qproj, energies);
  ks<<<dim3(NB), dim3(256), 0, stream>>>(energies, mask, wout);
  kc<<<dim3(NB, 4), dim3(256), 0, stream>>>(key, wout, ctx);
}

// Round 4
// 376.817 us; speedup vs baseline: 1.0831x; 1.0831x over previous
//
#include <hip/hip_runtime.h>
#include <hip/hip_bf16.h>
#include <math.h>

#define NB 64
#define NT 1024
#define NE 512
#define NR 1024
#define NA 128
#define NF 32
#define NK 31
#define CPAD 15
#define BN_EPS 1e-5f

typedef __attribute__((ext_vector_type(4))) float f32x4;
typedef __attribute__((ext_vector_type(8))) short bf16x8;

// ws byte offsets
#define WS_QPROJ 0               // 64*128 f32   = 32768
#define WS_ENERG 32768           // 64*1024 f32  = 262144
#define WS_WKHI  294912          // 512*128 bf16 = 131072 (B-fragment order)
#define WS_WKLO  425984          // 131072
#define WS_WLHI  557056          // 32*128 bf16  = 8192 (B-fragment order)
#define WS_WLLO  565248          // 8192
#define WS_PART  573440          // 64*8*512 f32 = 1048576

__device__ __forceinline__ ushort f2bf(float x) {
  union { float f; unsigned u; } v; v.f = x;
  unsigned r = v.u + 0x7fffu + ((v.u >> 16) & 1u);  // RTNE
  return (ushort)(r >> 16);
}
__device__ __forceinline__ float bf2f(ushort h) {
  union { unsigned u; float f; } v; v.u = ((unsigned)h) << 16; return v.f;
}

// ---- prep: Wk/Wloc -> bf16 hi/lo B-fragments in ws; qproj = query@Wq ----
// B-frag layout for 16x16x32: value (k-chunk kc, ntile n, lane l, j) =
//   W[kc*32 + (l>>4)*8 + j][n*16 + (l&15)], stored flat ((kc*8+n)*64+l)*8+j
__global__ __launch_bounds__(256) void kprep(
    const float* __restrict__ Wk, const float* __restrict__ Wloc,
    const float* __restrict__ query, const float* __restrict__ Wq,
    ushort* __restrict__ wkhi, ushort* __restrict__ wklo,
    ushort* __restrict__ wlhi, ushort* __restrict__ wllo,
    float* __restrict__ qproj) {
  __shared__ float qs[NR];
  __shared__ float part[128];
  const int blk = blockIdx.x;
  const int tid = threadIdx.x;
  if (blk < 16) {               // Wk fragments, one 32-k chunk per block
    const int kc = blk;
#pragma unroll
    for (int it = 0; it < 16; ++it) {
      int idx = it * 256 + tid;           // 0..4095
      int n = idx >> 9, l = (idx >> 3) & 63, j = idx & 7;
      int k = kc * 32 + ((l >> 4) * 8 + j);
      int a = n * 16 + (l & 15);
      float val = Wk[k * NA + a];
      ushort hi = f2bf(val);
      ushort lo = f2bf(val - bf2f(hi));
      int dst = ((kc * 8 + n) * 64 + l) * 8 + j;
      wkhi[dst] = hi; wklo[dst] = lo;
    }
  } else if (blk == 16) {       // Wloc fragments (single 32-k chunk, k=f)
#pragma unroll
    for (int it = 0; it < 16; ++it) {
      int idx = it * 256 + tid;
      int n = idx >> 9, l = (idx >> 3) & 63, j = idx & 7;
      int f = (l >> 4) * 8 + j;
      int a = n * 16 + (l & 15);
      float val = Wloc[f * NA + a];
      ushort hi = f2bf(val);
      ushort lo = f2bf(val - bf2f(hi));
      int dst = (n * 64 + l) * 8 + j;
      wlhi[dst] = hi; wllo[dst] = lo;
    }
  } else {                      // qproj for b = blk-17
    const int b = blk - 17;
    for (int i = tid; i < NR; i += 256) qs[i] = query[b * NR + i];
    __syncthreads();
    int a = tid & 127, h = tid >> 7;
    float acc = 0.f;
#pragma unroll 8
    for (int r = h * 512; r < h * 512 + 512; ++r) acc += qs[r] * Wq[r * NA + a];
    if (h) part[a] = acc;
    __syncthreads();
    if (!h) qproj[b * NA + a] = acc + part[a];
  }
}

// ---- energies[b,t] = tanh(q + key@Wk + featsT@Wloc) . v  (MFMA, split bf16) ----
__global__ __launch_bounds__(256) void ke(
    const float* __restrict__ key, const float* __restrict__ aw,
    const float* __restrict__ conv_w, const float* __restrict__ bn_g,
    const float* __restrict__ bn_b, const float* __restrict__ bn_m,
    const float* __restrict__ bn_v,
    const ushort* __restrict__ wkhi, const ushort* __restrict__ wklo,
    const ushort* __restrict__ wlhi, const ushort* __restrict__ wllo,
    const float* __restrict__ vvec, const float* __restrict__ qproj,
    float* __restrict__ energies) {
  __shared__ ushort khi[64 * 64];        // [t][e] bf16, byte ^= (t&7)<<4 ; reused as featsT hi
  __shared__ ushort klo[64 * 64];        // reused as featsT lo
  __shared__ float x_lds[2][64 + 2 * CPAD];
  __shared__ float q_lds[NA], v_lds[NA];

  const int b = blockIdx.x;
  const int t0 = blockIdx.y * 64;
  const int tid = threadIdx.x;
  const int l = tid & 63;
  const int w = tid >> 6;                // wave id: t rows [t0+w*16, +16)

  if (tid < 2 * 94) {
    int c = tid / 94, i = tid - c * 94;
    int t = t0 - CPAD + i;
    x_lds[c][i] = (t >= 0 && t < NT) ? aw[b * 2 * NT + c * NT + t] : 0.f;
  }
  if (tid < NA) {
    q_lds[tid] = qproj[b * NA + tid];
    v_lds[tid] = vvec[tid];
  }

  f32x4 acc[8];
#pragma unroll
  for (int n = 0; n < 8; ++n) acc[n] = (f32x4){0.f, 0.f, 0.f, 0.f};

  const float* kbase = key + (size_t)b * NT * NE + (size_t)t0 * NE;

  for (int ec = 0; ec < 8; ++ec) {       // K-chunks of 64
    __syncthreads();
    // stage key [64t][64e] f32 -> bf16 hi/lo, XOR-swizzled rows (stride 128B)
#pragma unroll
    for (int i = 0; i < 4; ++i) {
      int fi = i * 256 + tid;            // float4 index, 1024 total
      int row = fi >> 4, c4 = fi & 15;
      float4 v4 = *(const float4*)(kbase + (size_t)row * NE + ec * 64 + c4 * 4);
      ushort4 h4, lo4;
      h4.x = f2bf(v4.x); lo4.x = f2bf(v4.x - bf2f(h4.x));
      h4.y = f2bf(v4.y); lo4.y = f2bf(v4.y - bf2f(h4.y));
      h4.z = f2bf(v4.z); lo4.z = f2bf(v4.z - bf2f(h4.z));
      h4.w = f2bf(v4.w); lo4.w = f2bf(v4.w - bf2f(h4.w));
      int byteoff = (row * 128 + c4 * 8) ^ ((row & 7) << 4);
      *(ushort4*)((char*)khi + byteoff) = h4;
      *(ushort4*)((char*)klo + byteoff) = lo4;
    }
    __syncthreads();
#pragma unroll
    for (int h = 0; h < 2; ++h) {
      int kc = ec * 2 + h;
      // A-frag: row = w*16 + (l&15); within-row k bytes = h*64 + (l>>4)*16
      int abyte = (((w * 16 + (l & 15)) * 128) + h * 64 + ((l >> 4) * 16)) ^ ((l & 7) << 4);
      bf16x8 ahi = *(bf16x8*)((char*)khi + abyte);
      bf16x8 alo = *(bf16x8*)((char*)klo + abyte);
      const ushort* bh = wkhi + ((size_t)(kc * 8) * 64 + l) * 8;
      const ushort* bl = wklo + ((size_t)(kc * 8) * 64 + l) * 8;
#pragma unroll
      for (int n = 0; n < 8; ++n) {
        bf16x8 bhi = *(const bf16x8*)(bh + n * 512);
        bf16x8 blo = *(const bf16x8*)(bl + n * 512);
        acc[n] = __builtin_amdgcn_mfma_f32_16x16x32_bf16(ahi, bhi, acc[n], 0, 0, 0);
        acc[n] = __builtin_amdgcn_mfma_f32_16x16x32_bf16(ahi, blo, acc[n], 0, 0, 0);
        acc[n] = __builtin_amdgcn_mfma_f32_16x16x32_bf16(alo, bhi, acc[n], 0, 0, 0);
      }
    }
  }

  // ---- loc term as one extra K=32 MFMA step: featsT[t][f] hi/lo into reused LDS ----
  __syncthreads();  // done with khi/klo as key tiles
  {
    int t = tid & 63, f0 = (tid >> 6) * 8;
    ushort4 fh[2], fl[2];
#pragma unroll
    for (int ff = 0; ff < 8; ++ff) {
      int f = f0 + ff;
      float s = 0.f;
#pragma unroll
      for (int c = 0; c < 2; ++c)
#pragma unroll
        for (int k = 0; k < NK; ++k)
          s += conv_w[(f * 2 + c) * NK + k] * x_lds[c][t + k];
      s = fmaxf(s, 0.f);
      float scale = rsqrtf(bn_v[f] + BN_EPS) * bn_g[f];
      float bias = bn_b[f] - bn_m[f] * scale;
      s = s * scale + bias;
      ushort hi = f2bf(s);
      ushort lo = f2bf(s - bf2f(hi));
      ((ushort*)fh)[ff] = hi;
      ((ushort*)fl)[ff] = lo;
    }
    // featsT row t (stride 32 bf16 = 64B), byte ^= (t&3)<<4
    int base = (t * 64 + f0 * 2) ^ ((t & 3) << 4);
    *(ushort4*)((char*)khi + base) = fh[0];
    *(ushort4*)((char*)khi + base + 8) = fh[1];
    *(ushort4*)((char*)klo + base) = fl[0];
    *(ushort4*)((char*)klo + base + 8) = fl[1];
  }
  __syncthreads();
  {
    int abyte = ((w * 16 + (l & 15)) * 64 + ((l >> 4) * 16)) ^ ((l & 3) << 4);
    bf16x8 ahi = *(bf16x8*)((char*)khi + abyte);
    bf16x8 alo = *(bf16x8*)((char*)klo + abyte);
#pragma unroll
    for (int n = 0; n < 8; ++n) {
      bf16x8 bhi = *(const bf16x8*)(wlhi + (n * 64 + l) * 8);
      bf16x8 blo = *(const bf16x8*)(wllo + (n * 64 + l) * 8);
      acc[n] = __builtin_amdgcn_mfma_f32_16x16x32_bf16(ahi, bhi, acc[n], 0, 0, 0);
      acc[n] = __builtin_amdgcn_mfma_f32_16x16x32_bf16(ahi, blo, acc[n], 0, 0, 0);
      acc[n] = __builtin_amdgcn_mfma_f32_16x16x32_bf16(alo, bhi, acc[n], 0, 0, 0);
    }
  }

  // ---- epilogue: energies = sum_a tanh(acc + q[a]) * v[a] ----
  // C/D: col a = n*16 + (l&15), row t_local = w*16 + (l>>4)*4 + r
  float er[4] = {0.f, 0.f, 0.f, 0.f};
#pragma unroll
  for (int n = 0; n < 8; ++n) {
    int a = n * 16 + (l & 15);
    float qa = q_lds[a], va = v_lds[a];
#pragma unroll
    for (int r = 0; r < 4; ++r) er[r] += tanhf(acc[n][r] + qa) * va;
  }
#pragma unroll
  for (int r = 0; r < 4; ++r) {
    float s = er[r];
    s += __shfl_xor(s, 1, 16);
    s += __shfl_xor(s, 2, 16);
    s += __shfl_xor(s, 4, 16);
    s += __shfl_xor(s, 8, 16);
    if ((l & 15) == 0)
      energies[b * NT + t0 + w * 16 + (l >> 4) * 4 + r] = s;
  }
}

// ---------------- masked softmax over T ----------------
__global__ __launch_bounds__(256) void ks(const float* __restrict__ energies,
                                          const int* __restrict__ mask,
                                          float* __restrict__ wout) {
  __shared__ float redmax[4];
  __shared__ float redsum[4];
  int b = blockIdx.x;
  int tid = threadIdx.x;
  float vals[4];
  float mx = -INFINITY;
#pragma unroll
  for (int j = 0; j < 4; ++j) {
    int t = tid + j * 256;
    float e = energies[b * NT + t];
    if (mask[b * NT + t] != 0) e = -INFINITY;
    vals[j] = e;
    mx = fmaxf(mx, e);
  }
#pragma unroll
  for (int m = 1; m < 64; m <<= 1) mx = fmaxf(mx, __shfl_xor(mx, m, 64));
  if ((tid & 63) == 0) redmax[tid >> 6] = mx;
  __syncthreads();
  mx = fmaxf(fmaxf(redmax[0], redmax[1]), fmaxf(redmax[2], redmax[3]));
  float s = 0.f;
#pragma unroll
  for (int j = 0; j < 4; ++j) {
    float p = expf(vals[j] - mx);
    vals[j] = p;
    s += p;
  }
#pragma unroll
  for (int m = 1; m < 64; m <<= 1) s += __shfl_xor(s, m, 64);
  if ((tid & 63) == 0) redsum[tid >> 6] = s;
  __syncthreads();
  s = redsum[0] + redsum[1] + redsum[2] + redsum[3];
  float inv = 1.f / s;
#pragma unroll
  for (int j = 0; j < 4; ++j) wout[b * NT + tid + j * 256] = vals[j] * inv;
}

// ---------------- context: phase 1 partials over 128-t chunks ----------------
__global__ __launch_bounds__(256) void kc1(const float* __restrict__ key,
                                           const float* __restrict__ wout,
                                           float* __restrict__ part) {
  __shared__ float w_lds[128];
  int b = blockIdx.x, tc = blockIdx.y;
  int tid = threadIdx.x;
  if (tid < 128) w_lds[tid] = wout[b * NT + tc * 128 + tid];
  __syncthreads();
  const float* kp = key + (size_t)b * NT * NE + (size_t)tc * 128 * NE + tid;
  float a0 = 0.f, a1 = 0.f;
#pragma unroll 4
  for (int t = 0; t < 128; ++t) {
    float wv = w_lds[t];
    a0 += wv * kp[(size_t)t * NE];
    a1 += wv * kp[(size_t)t * NE + 256];
  }
  part[(b * 8 + tc) * NE + tid] = a0;
  part[(b * 8 + tc) * NE + tid + 256] = a1;
}

// ---------------- context: phase 2 reduce ----------------
__global__ __launch_bounds__(512) void kc2(const float* __restrict__ part,
                                           float* __restrict__ ctx) {
  int b = blockIdx.x, e = threadIdx.x;
  float s = 0.f;
#pragma unroll
  for (int tc = 0; tc < 8; ++tc) s += part[(b * 8 + tc) * NE + e];
  ctx[b * NE + e] = s;
}

extern "C" void kernel_launch(void* const* d_in, const int* in_sizes, int n_in,
                              void* d_out, int out_size, void* d_ws, size_t ws_size,
                              hipStream_t stream) {
  const float* query  = (const float*)d_in[0];
  const float* key    = (const float*)d_in[1];
  const float* aw     = (const float*)d_in[2];
  const int*   mask   = (const int*)d_in[3];
  const float* Wq     = (const float*)d_in[4];
  const float* Wk     = (const float*)d_in[5];
  const float* conv_w = (const float*)d_in[6];
  const float* bn_g   = (const float*)d_in[7];
  const float* bn_b   = (const float*)d_in[8];
  const float* bn_m   = (const float*)d_in[9];
  const float* bn_v   = (const float*)d_in[10];
  const float* Wloc   = (const float*)d_in[11];
  const float* vvec   = (const float*)d_in[12];

  float* ctx  = (float*)d_out;             // [B,E]
  float* wout = (float*)d_out + NB * NE;   // [B,T]

  char* ws = (char*)d_ws;
  float*  qproj    = (float*)(ws + WS_QPROJ);
  float*  energies = (float*)(ws + WS_ENERG);
  ushort* wkhi     = (ushort*)(ws + WS_WKHI);
  ushort* wklo     = (ushort*)(ws + WS_WKLO);
  ushort* wlhi     = (ushort*)(ws + WS_WLHI);
  ushort* wllo     = (ushort*)(ws + WS_WLLO);
  float*  partial  = (float*)(ws + WS_PART);

  kprep<<<dim3(17 + NB), dim3(256), 0, stream>>>(Wk, Wloc, query, Wq,
                                                 wkhi, wklo, wlhi, wllo, qproj);
  ke<<<dim3(NB, NT / 64), dim3(256), 0, stream>>>(
      key, aw, conv_w, bn_g, bn_b, bn_m, bn_v,
      wkhi, wklo, wlhi, wllo, vvec, qproj, energies);
  ks<<<dim3(NB), dim3(256), 0, stream>>>(energies, mask, wout);
  kc1<<<dim3(NB, 8), dim3(256), 0, stream>>>(key, wout, partial);
  kc2<<<dim3(NB), dim3(512), 0, stream>>>(partial, ctx);
}

// Round 6
// 298.162 us; speedup vs baseline: 1.3688x; 1.2638x over previous
//
#include <hip/hip_runtime.h>
#include <hip/hip_bf16.h>
#include <math.h>

#define NB 64
#define NT 1024
#define NE 512
#define NR 1024
#define NA 128
#define NF 32
#define NK 31
#define CPAD 15
#define BN_EPS 1e-5f

typedef __attribute__((ext_vector_type(4))) float f32x4;
typedef __attribute__((ext_vector_type(16))) float f32x16;
typedef __attribute__((ext_vector_type(8))) short bf16x8;
typedef __attribute__((ext_vector_type(8))) unsigned short ushort8v;

// ws byte offsets
#define WS_QPROJ 0               // 64*128 f32   = 32768
#define WS_ENERG 32768           // 64*1024 f32  = 262144
#define WS_WKHI  294912          // 65536 bf16   = 131072 (32x32x16 B-frag order)
#define WS_WKLO  425984          // 131072
#define WS_WLHI  557056          // 4096 bf16    = 8192 (B-frag order)
#define WS_WLLO  565248          // 8192
#define WS_PART  573440          // 64*8*512 f32 = 1048576

__device__ __forceinline__ ushort f2bf(float x) {
  union { float f; unsigned u; } v; v.f = x;
  unsigned r = v.u + 0x7fffu + ((v.u >> 16) & 1u);  // RTNE
  return (ushort)(r >> 16);
}
__device__ __forceinline__ float bf2f(ushort h) {
  union { unsigned u; float f; } v; v.u = ((unsigned)h) << 16; return v.f;
}
__device__ __forceinline__ float tanh_fast(float x) {
  float ax = fminf(fabsf(x), 15.f);
  float e = __expf(2.f * ax);
  float r = (e - 1.f) / (e + 1.f);
  return copysignf(r, x);
}

// ---- prep: Wk/Wloc -> bf16 hi/lo 32x32x16 B-fragments; qproj = query@Wq ----
// frag elem g: j=g&7, l=(g>>3)&63, n=(g>>9)&3, kk=g>>11
//   value = W[kk*16 + (l>>5)*8 + j][n*32 + (l&31)]
__global__ __launch_bounds__(256) void kprep(
    const float* __restrict__ Wk, const float* __restrict__ Wloc,
    const float* __restrict__ query, const float* __restrict__ Wq,
    ushort* __restrict__ wkhi, ushort* __restrict__ wklo,
    ushort* __restrict__ wlhi, ushort* __restrict__ wllo,
    float* __restrict__ qproj) {
  __shared__ float qs[NR];
  __shared__ float part[128];
  const int blk = blockIdx.x;
  const int tid = threadIdx.x;
  if (blk < 16) {               // Wk fragments
#pragma unroll
    for (int it = 0; it < 16; ++it) {
      int g = blk * 4096 + it * 256 + tid;
      int j = g & 7, l = (g >> 3) & 63, n = (g >> 9) & 3, kk = g >> 11;
      int k = kk * 16 + (l >> 5) * 8 + j;
      int a = n * 32 + (l & 31);
      float val = Wk[k * NA + a];
      ushort hi = f2bf(val);
      wkhi[g] = hi;
      wklo[g] = f2bf(val - bf2f(hi));
    }
  } else if (blk == 16) {       // Wloc fragments (2 kk-steps, k=f)
#pragma unroll
    for (int it = 0; it < 16; ++it) {
      int g = it * 256 + tid;   // < 4096
      int j = g & 7, l = (g >> 3) & 63, n = (g >> 9) & 3, kk = g >> 11;
      int f = kk * 16 + (l >> 5) * 8 + j;
      int a = n * 32 + (l & 31);
      float val = Wloc[f * NA + a];
      ushort hi = f2bf(val);
      wlhi[g] = hi;
      wllo[g] = f2bf(val - bf2f(hi));
    }
  } else {                      // qproj for b = blk-17
    const int b = blk - 17;
    for (int i = tid; i < NR; i += 256) qs[i] = query[b * NR + i];
    __syncthreads();
    int a = tid & 127, h = tid >> 7;
    float acc = 0.f;
#pragma unroll 8
    for (int r = h * 512; r < h * 512 + 512; ++r) acc += qs[r] * Wq[r * NA + a];
    if (h) part[a] = acc;
    __syncthreads();
    if (!h) qproj[b * NA + a] = acc + part[a];
  }
}

// ---- energies[b,t] = tanh(q + key@Wk + featsT@Wloc) . v  (32x32x16 MFMA) ----
__global__ __launch_bounds__(256, 2) void ke(
    const float* __restrict__ key, const float* __restrict__ aw,
    const float* __restrict__ conv_w, const float* __restrict__ bn_g,
    const float* __restrict__ bn_b, const float* __restrict__ bn_m,
    const float* __restrict__ bn_v,
    const ushort* __restrict__ wkhi, const ushort* __restrict__ wklo,
    const ushort* __restrict__ wlhi, const ushort* __restrict__ wllo,
    const float* __restrict__ vvec, const float* __restrict__ qproj,
    float* __restrict__ energies) {
  __shared__ ushort khi[128 * 64];   // key tile [row][k] bf16, byte ^= (row&7)<<4; reused featsT
  __shared__ ushort klo[128 * 64];
  __shared__ ushort bhl[8192];       // Wk chunk hi, frag order [kk4][n4][l64][j8]
  __shared__ ushort bll[8192];       // lo
  __shared__ float x_lds[2][160];    // conv input slice (158 used)
  __shared__ float cw[NF * 2 * NK];  // conv weights (1984 floats)
  __shared__ float q_lds[NA], v_lds[NA];

  const int b = blockIdx.x;
  const int t0 = blockIdx.y * 128;
  const int tid = threadIdx.x;
  const int l = tid & 63;
  const int w = tid >> 6;            // wave: rows [t0+w*32, +32)

  for (int i = tid; i < 2 * 158; i += 256) {
    int c = i / 158, p = i - c * 158;
    int t = t0 - CPAD + p;
    x_lds[c][p] = (t >= 0 && t < NT) ? aw[b * 2 * NT + c * NT + t] : 0.f;
  }
  for (int i = tid; i < NF * 2 * NK; i += 256) cw[i] = conv_w[i];
  if (tid < NA) {
    q_lds[tid] = qproj[b * NA + tid];
    v_lds[tid] = vvec[tid];
  }

  f32x16 acc[4];
#pragma unroll
  for (int n = 0; n < 4; ++n)
#pragma unroll
    for (int r = 0; r < 16; ++r) acc[n][r] = 0.f;

  const float* kbase = key + (size_t)b * NT * NE + (size_t)t0 * NE;

  for (int ec = 0; ec < 8; ++ec) {   // K-chunks of 64
    __syncthreads();
    // stage key [128t][64k] f32 -> bf16 hi/lo, XOR-swizzled rows
#pragma unroll
    for (int i = 0; i < 8; ++i) {
      int fi = i * 256 + tid;        // float4 index, 2048 total
      int row = fi >> 4, c4 = fi & 15;
      float4 v4 = *(const float4*)(kbase + (size_t)row * NE + ec * 64 + c4 * 4);
      ushort4 h4, lo4;
      h4.x = f2bf(v4.x); lo4.x = f2bf(v4.x - bf2f(h4.x));
      h4.y = f2bf(v4.y); lo4.y = f2bf(v4.y - bf2f(h4.y));
      h4.z = f2bf(v4.z); lo4.z = f2bf(v4.z - bf2f(h4.z));
      h4.w = f2bf(v4.w); lo4.w = f2bf(v4.w - bf2f(h4.w));
      int byteoff = (row * 128 + c4 * 8) ^ ((row & 7) << 4);
      *(ushort4*)((char*)khi + byteoff) = h4;
      *(ushort4*)((char*)klo + byteoff) = lo4;
    }
    // stage Wk chunk fragments (contiguous 16KB hi + 16KB lo)
    {
      const ushort8v* sh = (const ushort8v*)(wkhi + ec * 8192);
      const ushort8v* sl = (const ushort8v*)(wklo + ec * 8192);
#pragma unroll
      for (int i = 0; i < 4; ++i) {
        int idx = i * 256 + tid;     // 1024 vecs of 8 ushorts
        ((ushort8v*)bhl)[idx] = sh[idx];
        ((ushort8v*)bll)[idx] = sl[idx];
      }
    }
    __syncthreads();
#pragma unroll
    for (int kk = 0; kk < 4; ++kk) {
      int row = w * 32 + (l & 31);
      int abyte = (row * 128 + kk * 32 + ((l >> 5) * 16)) ^ ((l & 7) << 4);
      bf16x8 ahi = *(bf16x8*)((char*)khi + abyte);
      bf16x8 alo = *(bf16x8*)((char*)klo + abyte);
#pragma unroll
      for (int n = 0; n < 4; ++n) {
        bf16x8 bh = *(bf16x8*)(bhl + ((kk * 4 + n) * 64 + l) * 8);
        bf16x8 bl = *(bf16x8*)(bll + ((kk * 4 + n) * 64 + l) * 8);
        acc[n] = __builtin_amdgcn_mfma_f32_32x32x16_bf16(ahi, bh, acc[n], 0, 0, 0);
        acc[n] = __builtin_amdgcn_mfma_f32_32x32x16_bf16(ahi, bl, acc[n], 0, 0, 0);
        acc[n] = __builtin_amdgcn_mfma_f32_32x32x16_bf16(alo, bh, acc[n], 0, 0, 0);
      }
    }
  }

  // ---- loc term: featsT[t][f] (A, 2 k-steps) @ Wloc frags (B) ----
  __syncthreads();   // khi/klo and bhl/bll free
  {
    const ushort8v* sh = (const ushort8v*)wlhi;
    const ushort8v* sl = (const ushort8v*)wllo;
#pragma unroll
    for (int i = 0; i < 2; ++i) {
      int idx = i * 256 + tid;       // 512 vecs
      ((ushort8v*)bhl)[idx] = sh[idx];
      ((ushort8v*)bll)[idx] = sl[idx];
    }
  }
  {
    int t = tid & 127, fg = tid >> 7;   // 16 f per thread
    ushort8v fh[2], fl[2];
#pragma unroll
    for (int ff = 0; ff < 16; ++ff) {
      int f = fg * 16 + ff;
      float s = 0.f;
#pragma unroll
      for (int c = 0; c < 2; ++c)
#pragma unroll
        for (int k = 0; k < NK; ++k)
          s += cw[(f * 2 + c) * NK + k] * x_lds[c][t + k];
      s = fmaxf(s, 0.f);
      float scale = rsqrtf(bn_v[f] + BN_EPS) * bn_g[f];
      float bias = bn_b[f] - bn_m[f] * scale;
      s = s * scale + bias;
      ushort hi = f2bf(s);
      ((ushort*)fh)[ff] = hi;
      ((ushort*)fl)[ff] = f2bf(s - bf2f(hi));
    }
    // featsT row t: 32 f, stride 64B; two 16B blocks, byte ^= (t&7)<<4
    int base0 = (t * 64 + fg * 32) ^ ((t & 7) << 4);
    int base1 = (t * 64 + fg * 32 + 16) ^ ((t & 7) << 4);
    *(ushort8v*)((char*)khi + base0) = fh[0];
    *(ushort8v*)((char*)khi + base1) = fh[1];
    *(ushort8v*)((char*)klo + base0) = fl[0];
    *(ushort8v*)((char*)klo + base1) = fl[1];
  }
  __syncthreads();
#pragma unroll
  for (int kk = 0; kk < 2; ++kk) {
    int row = w * 32 + (l & 31);
    int abyte = (row * 64 + kk * 32 + ((l >> 5) * 16)) ^ ((row & 7) << 4);
    bf16x8 ahi = *(bf16x8*)((char*)khi + abyte);
    bf16x8 alo = *(bf16x8*)((char*)klo + abyte);
#pragma unroll
    for (int n = 0; n < 4; ++n) {
      bf16x8 bh = *(bf16x8*)(bhl + ((kk * 4 + n) * 64 + l) * 8);
      bf16x8 bl = *(bf16x8*)(bll + ((kk * 4 + n) * 64 + l) * 8);
      acc[n] = __builtin_amdgcn_mfma_f32_32x32x16_bf16(ahi, bh, acc[n], 0, 0, 0);
      acc[n] = __builtin_amdgcn_mfma_f32_32x32x16_bf16(ahi, bl, acc[n], 0, 0, 0);
      acc[n] = __builtin_amdgcn_mfma_f32_32x32x16_bf16(alo, bh, acc[n], 0, 0, 0);
    }
  }

  // ---- epilogue: energies = sum_a tanh(acc + q[a]) * v[a] ----
  // D: col a = n*32 + (l&31), row t = w*32 + 4*(l>>5) + (r&3) + 8*(r>>2)
  float er[16];
#pragma unroll
  for (int r = 0; r < 16; ++r) er[r] = 0.f;
#pragma unroll
  for (int n = 0; n < 4; ++n) {
    int a = n * 32 + (l & 31);
    float qa = q_lds[a], va = v_lds[a];
#pragma unroll
    for (int r = 0; r < 16; ++r) er[r] += tanh_fast(acc[n][r] + qa) * va;
  }
#pragma unroll
  for (int r = 0; r < 16; ++r) {
    float s = er[r];
    s += __shfl_xor(s, 1, 64);
    s += __shfl_xor(s, 2, 64);
    s += __shfl_xor(s, 4, 64);
    s += __shfl_xor(s, 8, 64);
    s += __shfl_xor(s, 16, 64);
    if ((l & 31) == 0)
      energies[b * NT + t0 + w * 32 + 4 * (l >> 5) + (r & 3) + 8 * (r >> 2)] = s;
  }
}

// ---------------- masked softmax over T ----------------
__global__ __launch_bounds__(256) void ks(const float* __restrict__ energies,
                                          const int* __restrict__ mask,
                                          float* __restrict__ wout) {
  __shared__ float redmax[4];
  __shared__ float redsum[4];
  int b = blockIdx.x;
  int tid = threadIdx.x;
  float vals[4];
  float mx = -INFINITY;
#pragma unroll
  for (int j = 0; j < 4; ++j) {
    int t = tid + j * 256;
    float e = energies[b * NT + t];
    if (mask[b * NT + t] != 0) e = -INFINITY;
    vals[j] = e;
    mx = fmaxf(mx, e);
  }
#pragma unroll
  for (int m = 1; m < 64; m <<= 1) mx = fmaxf(mx, __shfl_xor(mx, m, 64));
  if ((tid & 63) == 0) redmax[tid >> 6] = mx;
  __syncthreads();
  mx = fmaxf(fmaxf(redmax[0], redmax[1]), fmaxf(redmax[2], redmax[3]));
  float s = 0.f;
#pragma unroll
  for (int j = 0; j < 4; ++j) {
    float p = expf(vals[j] - mx);
    vals[j] = p;
    s += p;
  }
#pragma unroll
  for (int m = 1; m < 64; m <<= 1) s += __shfl_xor(s, m, 64);
  if ((tid & 63) == 0) redsum[tid >> 6] = s;
  __syncthreads();
  s = redsum[0] + redsum[1] + redsum[2] + redsum[3];
  float inv = 1.f / s;
#pragma unroll
  for (int j = 0; j < 4; ++j) wout[b * NT + tid + j * 256] = vals[j] * inv;
}

// ---------------- context: phase 1 partials over 128-t chunks ----------------
__global__ __launch_bounds__(256) void kc1(const float* __restrict__ key,
                                           const float* __restrict__ wout,
                                           float* __restrict__ part) {
  __shared__ float w_lds[128];
  int b = blockIdx.x, tc = blockIdx.y;
  int tid = threadIdx.x;
  if (tid < 128) w_lds[tid] = wout[b * NT + tc * 128 + tid];
  __syncthreads();
  const float* kp = key + (size_t)b * NT * NE + (size_t)tc * 128 * NE + tid;
  float a0 = 0.f, a1 = 0.f;
#pragma unroll 8
  for (int t = 0; t < 128; ++t) {
    float wv = w_lds[t];
    a0 += wv * kp[(size_t)t * NE];
    a1 += wv * kp[(size_t)t * NE + 256];
  }
  part[(b * 8 + tc) * NE + tid] = a0;
  part[(b * 8 + tc) * NE + tid + 256] = a1;
}

// ---------------- context: phase 2 reduce ----------------
__global__ __launch_bounds__(512) void kc2(const float* __restrict__ part,
                                           float* __restrict__ ctx) {
  int b = blockIdx.x, e = threadIdx.x;
  float s = 0.f;
#pragma unroll
  for (int tc = 0; tc < 8; ++tc) s += part[(b * 8 + tc) * NE + e];
  ctx[b * NE + e] = s;
}

extern "C" void kernel_launch(void* const* d_in, const int* in_sizes, int n_in,
                              void* d_out, int out_size, void* d_ws, size_t ws_size,
                              hipStream_t stream) {
  const float* query  = (const float*)d_in[0];
  const float* key    = (const float*)d_in[1];
  const float* aw     = (const float*)d_in[2];
  const int*   mask   = (const int*)d_in[3];
  const float* Wq     = (const float*)d_in[4];
  const float* Wk     = (const float*)d_in[5];
  const float* conv_w = (const float*)d_in[6];
  const float* bn_g   = (const float*)d_in[7];
  const float* bn_b   = (const float*)d_in[8];
  const float* bn_m   = (const float*)d_in[9];
  const float* bn_v   = (const float*)d_in[10];
  const float* Wloc   = (const float*)d_in[11];
  const float* vvec   = (const float*)d_in[12];

  float* ctx  = (float*)d_out;             // [B,E]
  float* wout = (float*)d_out + NB * NE;   // [B,T]

  char* ws = (char*)d_ws;
  float*  qproj    = (float*)(ws + WS_QPROJ);
  float*  energies = (float*)(ws + WS_ENERG);
  ushort* wkhi     = (ushort*)(ws + WS_WKHI);
  ushort* wklo     = (ushort*)(ws + WS_WKLO);
  ushort* wlhi     = (ushort*)(ws + WS_WLHI);
  ushort* wllo     = (ushort*)(ws + WS_WLLO);
  float*  partial  = (float*)(ws + WS_PART);

  kprep<<<dim3(17 + NB), dim3(256), 0, stream>>>(Wk, Wloc, query, Wq,
                                                 wkhi, wklo, wlhi, wllo, qproj);
  ke<<<dim3(NB, NT / 128), dim3(256), 0, stream>>>(
      key, aw, conv_w, bn_g, bn_b, bn_m, bn_v,
      wkhi, wklo, wlhi, wllo, vvec, qproj, energies);
  ks<<<dim3(NB), dim3(256), 0, stream>>>(energies, mask, wout);
  kc1<<<dim3(NB, 8), dim3(256), 0, stream>>>(key, wout, partial);
  kc2<<<dim3(NB), dim3(512), 0, stream>>>(partial, ctx);
}

// Round 8
// 296.430 us; speedup vs baseline: 1.3768x; 1.0058x over previous
//
#include <hip/hip_runtime.h>
#include <hip/hip_bf16.h>
#include <math.h>

#define NB 64
#define NT 1024
#define NE 512
#define NR 1024
#define NA 128
#define NF 32
#define NK 31
#define CPAD 15
#define BN_EPS 1e-5f

typedef __attribute__((ext_vector_type(4))) float f32x4;
typedef __attribute__((ext_vector_type(16))) float f32x16;
typedef __attribute__((ext_vector_type(8))) short bf16x8;
typedef __attribute__((ext_vector_type(8))) unsigned short ushort8v;

// ws byte offsets
#define WS_QPROJ 0               // 64*128 f32   = 32768
#define WS_ENERG 32768           // 64*1024 f32  = 262144
#define WS_WKHI  294912          // 65536 bf16   = 131072 (32x32x16 B-frag order)
#define WS_WKLO  425984          // 131072
#define WS_WLHI  557056          // 4096 bf16    = 8192 (B-frag order)
#define WS_WLLO  565248          // 8192
#define WS_PART  573440          // 64*16*512 f32 = 2097152

__device__ __forceinline__ ushort f2bf(float x) {
  union { float f; unsigned u; } v; v.f = x;
  unsigned r = v.u + 0x7fffu + ((v.u >> 16) & 1u);  // RTNE
  return (ushort)(r >> 16);
}
__device__ __forceinline__ float bf2f(ushort h) {
  union { unsigned u; float f; } v; v.u = ((unsigned)h) << 16; return v.f;
}
__device__ __forceinline__ float tanh_fast(float x) {
  float ax = fminf(fabsf(x), 15.f);
  float e = __expf(2.f * ax);
  float r = (e - 1.f) / (e + 1.f);
  return copysignf(r, x);
}

#define FENCE() asm volatile("" ::: "memory")
#define WAIT_LGKM0() asm volatile("s_waitcnt lgkmcnt(0)" ::: "memory")

// ---- prep: Wk/Wloc -> bf16 hi/lo 32x32x16 B-fragments; qproj = query@Wq ----
// frag elem g: j=g&7, l=(g>>3)&63, n=(g>>9)&3, kk=g>>11
//   value = W[kk*16 + (l>>5)*8 + j][n*32 + (l&31)]
__global__ __launch_bounds__(256) void kprep(
    const float* __restrict__ Wk, const float* __restrict__ Wloc,
    const float* __restrict__ query, const float* __restrict__ Wq,
    ushort* __restrict__ wkhi, ushort* __restrict__ wklo,
    ushort* __restrict__ wlhi, ushort* __restrict__ wllo,
    float* __restrict__ qproj) {
  __shared__ float qs[NR];
  __shared__ float part[128];
  const int blk = blockIdx.x;
  const int tid = threadIdx.x;
  if (blk < 16) {               // Wk fragments
#pragma unroll
    for (int it = 0; it < 16; ++it) {
      int g = blk * 4096 + it * 256 + tid;
      int j = g & 7, l = (g >> 3) & 63, n = (g >> 9) & 3, kk = g >> 11;
      int k = kk * 16 + (l >> 5) * 8 + j;
      int a = n * 32 + (l & 31);
      float val = Wk[k * NA + a];
      ushort hi = f2bf(val);
      wkhi[g] = hi;
      wklo[g] = f2bf(val - bf2f(hi));
    }
  } else if (blk == 16) {       // Wloc fragments (2 kk-steps, k=f)
#pragma unroll
    for (int it = 0; it < 16; ++it) {
      int g = it * 256 + tid;   // < 4096
      int j = g & 7, l = (g >> 3) & 63, n = (g >> 9) & 3, kk = g >> 11;
      int f = kk * 16 + (l >> 5) * 8 + j;
      int a = n * 32 + (l & 31);
      float val = Wloc[f * NA + a];
      ushort hi = f2bf(val);
      wlhi[g] = hi;
      wllo[g] = f2bf(val - bf2f(hi));
    }
  } else {                      // qproj for b = blk-17
    const int b = blk - 17;
    for (int i = tid; i < NR; i += 256) qs[i] = query[b * NR + i];
    __syncthreads();
    int a = tid & 127, h = tid >> 7;
    float acc = 0.f;
#pragma unroll 8
    for (int r = h * 512; r < h * 512 + 512; ++r) acc += qs[r] * Wq[r * NA + a];
    if (h) part[a] = acc;
    __syncthreads();
    if (!h) qproj[b * NA + a] = acc + part[a];
  }
}

// ---- ke helpers ----
__device__ __forceinline__ void issue_kr(const float* kbase, int ec, int tid,
                                         f32x4 kr[8]) {
#pragma unroll
  for (int i = 0; i < 8; ++i) {
    int fi = i * 256 + tid;
    int row = fi >> 4, c4 = fi & 15;
    kr[i] = *(const f32x4*)(kbase + (size_t)row * NE + ec * 64 + c4 * 4);
  }
}

__device__ __forceinline__ void cw_tile(const f32x4 kr[8], int tid,
                                        ushort* khi, ushort* klo) {
#pragma unroll
  for (int i = 0; i < 8; ++i) {
    int fi = i * 256 + tid;
    int row = fi >> 4, c4 = fi & 15;
    f32x4 v4 = kr[i];
    ushort4 h4, lo4;
    h4.x = f2bf(v4.x); lo4.x = f2bf(v4.x - bf2f(h4.x));
    h4.y = f2bf(v4.y); lo4.y = f2bf(v4.y - bf2f(h4.y));
    h4.z = f2bf(v4.z); lo4.z = f2bf(v4.z - bf2f(h4.z));
    h4.w = f2bf(v4.w); lo4.w = f2bf(v4.w - bf2f(h4.w));
    int byteoff = (row * 128 + c4 * 8) ^ ((row & 7) << 4);
    *(ushort4*)((char*)khi + byteoff) = h4;
    *(ushort4*)((char*)klo + byteoff) = lo4;
  }
}

// async copy 4KB of B-fragments for this wave into LDS (linear layout)
__device__ __forceinline__ void stage_B(const ushort* src_base, ushort* lds_base,
                                        int wv, int lane) {
#pragma unroll
  for (int p = 0; p < 4; ++p) {
    const ushort* g = src_base + wv * 2048 + p * 512 + lane * 8;
    ushort* d = lds_base + wv * 2048 + p * 512;
    __builtin_amdgcn_global_load_lds(
        (const __attribute__((address_space(1))) unsigned int*)g,
        (__attribute__((address_space(3))) unsigned int*)d, 16, 0, 0);
  }
}

// ---- energies[b,t] = tanh(q + key@Wk + featsT@Wloc) . v  (32x32x16 MFMA) ----
__global__ __launch_bounds__(256, 2) void ke(
    const float* __restrict__ key, const float* __restrict__ aw,
    const float* __restrict__ conv_w, const float* __restrict__ bn_g,
    const float* __restrict__ bn_b, const float* __restrict__ bn_m,
    const float* __restrict__ bn_v,
    const ushort* __restrict__ wkhi, const ushort* __restrict__ wklo,
    const ushort* __restrict__ wlhi, const ushort* __restrict__ wllo,
    const float* __restrict__ vvec, const float* __restrict__ qproj,
    float* __restrict__ energies) {
  __shared__ ushort khi[128 * 64];   // key tile [row][k] bf16, byte ^= (row&7)<<4; reused featsT
  __shared__ ushort klo[128 * 64];
  __shared__ ushort bhl[8192];       // Wk chunk hi, frag order [kk4][n4][l64][j8]
  __shared__ ushort bll[8192];       // lo
  __shared__ float x_lds[2][160];    // conv input slice (158 used)
  __shared__ float cw[NF * 2 * NK];  // conv weights
  __shared__ float q_lds[NA], v_lds[NA];

  const int b = blockIdx.x;
  const int t0 = blockIdx.y * 128;
  const int tid = threadIdx.x;
  const int l = tid & 63;
  const int w = tid >> 6;            // wave: rows [t0+w*32, +32)

  for (int i = tid; i < 2 * 158; i += 256) {
    int c = i / 158, p = i - c * 158;
    int t = t0 - CPAD + p;
    x_lds[c][p] = (t >= 0 && t < NT) ? aw[b * 2 * NT + c * NT + t] : 0.f;
  }
  for (int i = tid; i < NF * 2 * NK; i += 256) cw[i] = conv_w[i];
  if (tid < NA) {
    q_lds[tid] = qproj[b * NA + tid];
    v_lds[tid] = vvec[tid];
  }

  f32x16 acc[4];
#pragma unroll
  for (int n = 0; n < 4; ++n)
#pragma unroll
    for (int r = 0; r < 16; ++r) acc[n][r] = 0.f;

  const float* kbase = key + (size_t)b * NT * NE + (size_t)t0 * NE;

  __syncthreads();   // drain misc staging; from here vmem counts are controlled

  // ---- pipelined staging: tile 0 ----
  f32x4 kr[8];
  issue_kr(kbase, 0, tid, kr);               // 8 vmem (oldest)
  stage_B(wkhi + 0, bhl, w, l);              // 8 gll
  stage_B(wklo + 0, bll, w, l);
  cw_tile(kr, tid, khi, klo);                // compiler waits kr only
  issue_kr(kbase, 1, tid, kr);               // next tile in flight
  asm volatile("s_waitcnt vmcnt(8)" ::: "memory");   // gll(0) landed
  WAIT_LGKM0();
  __builtin_amdgcn_s_barrier();
  FENCE();

  for (int ec = 0; ec < 8; ++ec) {
    // ---- MFMA phase on tile ec (kr for tile ec+1 in flight) ----
#pragma unroll
    for (int kk = 0; kk < 4; ++kk) {
      int row = w * 32 + (l & 31);
      int abyte = (row * 128 + kk * 32 + ((l >> 5) * 16)) ^ ((l & 7) << 4);
      bf16x8 ahi = *(bf16x8*)((char*)khi + abyte);
      bf16x8 alo = *(bf16x8*)((char*)klo + abyte);
#pragma unroll
      for (int n = 0; n < 4; ++n) {
        bf16x8 bh = *(bf16x8*)(bhl + ((kk * 4 + n) * 64 + l) * 8);
        bf16x8 bl = *(bf16x8*)(bll + ((kk * 4 + n) * 64 + l) * 8);
        acc[n] = __builtin_amdgcn_mfma_f32_32x32x16_bf16(ahi, bh, acc[n], 0, 0, 0);
        acc[n] = __builtin_amdgcn_mfma_f32_32x32x16_bf16(ahi, bl, acc[n], 0, 0, 0);
        acc[n] = __builtin_amdgcn_mfma_f32_32x32x16_bf16(alo, bh, acc[n], 0, 0, 0);
      }
    }
    WAIT_LGKM0();
    __builtin_amdgcn_s_barrier();            // all waves done reading tile ec
    FENCE();
    if (ec < 7) {
      stage_B(wkhi + (ec + 1) * 8192, bhl, w, l);   // 8 gll
      stage_B(wklo + (ec + 1) * 8192, bll, w, l);
      cw_tile(kr, tid, khi, klo);            // convert tile ec+1 (kr oldest)
      if (ec < 6) {
        issue_kr(kbase, ec + 2, tid, kr);    // tile ec+2 in flight
        asm volatile("s_waitcnt vmcnt(8)" ::: "memory");  // gll(ec+1) landed
      } else {
        asm volatile("s_waitcnt vmcnt(0)" ::: "memory");
      }
      WAIT_LGKM0();
      __builtin_amdgcn_s_barrier();          // tile ec+1 ready
      FENCE();
    }
  }

  // ---- loc term: featsT[t][f] (A, 2 k-steps) @ Wloc frags (B) ----
  FENCE();
  {
    const ushort8v* sh = (const ushort8v*)wlhi;
    const ushort8v* sl = (const ushort8v*)wllo;
#pragma unroll
    for (int i = 0; i < 2; ++i) {
      int idx = i * 256 + tid;       // 512 vecs
      ((ushort8v*)bhl)[idx] = sh[idx];
      ((ushort8v*)bll)[idx] = sl[idx];
    }
  }
  {
    int t = tid & 127, fg = tid >> 7;   // 16 f per thread
    ushort8v fh[2], fl[2];
#pragma unroll
    for (int ff = 0; ff < 16; ++ff) {
      int f = fg * 16 + ff;
      float s = 0.f;
#pragma unroll
      for (int c = 0; c < 2; ++c)
#pragma unroll
        for (int k = 0; k < NK; ++k)
          s += cw[(f * 2 + c) * NK + k] * x_lds[c][t + k];
      s = fmaxf(s, 0.f);
      float scale = rsqrtf(bn_v[f] + BN_EPS) * bn_g[f];
      float bias = bn_b[f] - bn_m[f] * scale;
      s = s * scale + bias;
      ushort hi = f2bf(s);
      ((ushort*)fh)[ff] = hi;
      ((ushort*)fl)[ff] = f2bf(s - bf2f(hi));
    }
    // featsT row t: 32 f, stride 64B; two 16B blocks, byte ^= (t&7)<<4
    int base0 = (t * 64 + fg * 32) ^ ((t & 7) << 4);
    int base1 = (t * 64 + fg * 32 + 16) ^ ((t & 7) << 4);
    *(ushort8v*)((char*)khi + base0) = fh[0];
    *(ushort8v*)((char*)khi + base1) = fh[1];
    *(ushort8v*)((char*)klo + base0) = fl[0];
    *(ushort8v*)((char*)klo + base1) = fl[1];
  }
  __syncthreads();
#pragma unroll
  for (int kk = 0; kk < 2; ++kk) {
    int row = w * 32 + (l & 31);
    int abyte = ((row * 64 + kk * 32 + ((l >> 5) * 16))) ^ ((row & 7) << 4);
    bf16x8 ahi = *(bf16x8*)((char*)khi + abyte);
    bf16x8 alo = *(bf16x8*)((char*)klo + abyte);
#pragma unroll
    for (int n = 0; n < 4; ++n) {
      bf16x8 bh = *(bf16x8*)(bhl + ((kk * 4 + n) * 64 + l) * 8);
      bf16x8 bl = *(bf16x8*)(bll + ((kk * 4 + n) * 64 + l) * 8);
      acc[n] = __builtin_amdgcn_mfma_f32_32x32x16_bf16(ahi, bh, acc[n], 0, 0, 0);
      acc[n] = __builtin_amdgcn_mfma_f32_32x32x16_bf16(ahi, bl, acc[n], 0, 0, 0);
      acc[n] = __builtin_amdgcn_mfma_f32_32x32x16_bf16(alo, bh, acc[n], 0, 0, 0);
    }
  }

  // ---- epilogue: energies = sum_a tanh(acc + q[a]) * v[a] ----
  // D: col a = n*32 + (l&31), row t = w*32 + 4*(l>>5) + (r&3) + 8*(r>>2)
  float er[16];
#pragma unroll
  for (int r = 0; r < 16; ++r) er[r] = 0.f;
#pragma unroll
  for (int n = 0; n < 4; ++n) {
    int a = n * 32 + (l & 31);
    float qa = q_lds[a], va = v_lds[a];
#pragma unroll
    for (int r = 0; r < 16; ++r) er[r] += tanh_fast(acc[n][r] + qa) * va;
  }
#pragma unroll
  for (int r = 0; r < 16; ++r) {
    float s = er[r];
    s += __shfl_xor(s, 1, 64);
    s += __shfl_xor(s, 2, 64);
    s += __shfl_xor(s, 4, 64);
    s += __shfl_xor(s, 8, 64);
    s += __shfl_xor(s, 16, 64);
    if ((l & 31) == 0)
      energies[b * NT + t0 + w * 32 + 4 * (l >> 5) + (r & 3) + 8 * (r >> 2)] = s;
  }
}

// ---------------- masked softmax over T ----------------
__global__ __launch_bounds__(256) void ks(const float* __restrict__ energies,
                                          const int* __restrict__ mask,
                                          float* __restrict__ wout) {
  __shared__ float redmax[4];
  __shared__ float redsum[4];
  int b = blockIdx.x;
  int tid = threadIdx.x;
  float vals[4];
  float mx = -INFINITY;
#pragma unroll
  for (int j = 0; j < 4; ++j) {
    int t = tid + j * 256;
    float e = energies[b * NT + t];
    if (mask[b * NT + t] != 0) e = -INFINITY;
    vals[j] = e;
    mx = fmaxf(mx, e);
  }
#pragma unroll
  for (int m = 1; m < 64; m <<= 1) mx = fmaxf(mx, __shfl_xor(mx, m, 64));
  if ((tid & 63) == 0) redmax[tid >> 6] = mx;
  __syncthreads();
  mx = fmaxf(fmaxf(redmax[0], redmax[1]), fmaxf(redmax[2], redmax[3]));
  float s = 0.f;
#pragma unroll
  for (int j = 0; j < 4; ++j) {
    float p = expf(vals[j] - mx);
    vals[j] = p;
    s += p;
  }
#pragma unroll
  for (int m = 1; m < 64; m <<= 1) s += __shfl_xor(s, m, 64);
  if ((tid & 63) == 0) redsum[tid >> 6] = s;
  __syncthreads();
  s = redsum[0] + redsum[1] + redsum[2] + redsum[3];
  float inv = 1.f / s;
#pragma unroll
  for (int j = 0; j < 4; ++j) wout[b * NT + tid + j * 256] = vals[j] * inv;
}

// ---------------- context: phase 1 partials over 64-t chunks ----------------
__global__ __launch_bounds__(256) void kc1(const float* __restrict__ key,
                                           const float* __restrict__ wout,
                                           float* __restrict__ part) {
  __shared__ float w_lds[64];
  __shared__ f32x4 red[128];
  int b = blockIdx.x, tc = blockIdx.y;   // grid (64,16)
  int tid = threadIdx.x;
  if (tid < 64) w_lds[tid] = wout[b * NT + tc * 64 + tid];
  __syncthreads();
  int e4 = (tid & 127) * 4, th = tid >> 7;
  const float* kp = key + (size_t)b * NT * NE + (size_t)(tc * 64 + th * 32) * NE + e4;
  f32x4 acc = (f32x4){0.f, 0.f, 0.f, 0.f};
#pragma unroll 8
  for (int t = 0; t < 32; ++t) {
    float wv = w_lds[th * 32 + t];
    f32x4 k4 = *(const f32x4*)(kp + (size_t)t * NE);
    acc += wv * k4;
  }
  if (th) red[tid & 127] = acc;
  __syncthreads();
  if (!th) {
    acc += red[tid];
    *(f32x4*)&part[((size_t)(b * 16 + tc)) * NE + e4] = acc;
  }
}

// ---------------- context: phase 2 reduce ----------------
__global__ __launch_bounds__(512) void kc2(const float* __restrict__ part,
                                           float* __restrict__ ctx) {
  int b = blockIdx.x, e = threadIdx.x;
  float s = 0.f;
#pragma unroll
  for (int tc = 0; tc < 16; ++tc) s += part[(b * 16 + tc) * NE + e];
  ctx[b * NE + e] = s;
}

extern "C" void kernel_launch(void* const* d_in, const int* in_sizes, int n_in,
                              void* d_out, int out_size, void* d_ws, size_t ws_size,
                              hipStream_t stream) {
  const float* query  = (const float*)d_in[0];
  const float* key    = (const float*)d_in[1];
  const float* aw     = (const float*)d_in[2];
  const int*   mask   = (const int*)d_in[3];
  const float* Wq     = (const float*)d_in[4];
  const float* Wk     = (const float*)d_in[5];
  const float* conv_w = (const float*)d_in[6];
  const float* bn_g   = (const float*)d_in[7];
  const float* bn_b   = (const float*)d_in[8];
  const float* bn_m   = (const float*)d_in[9];
  const float* bn_v   = (const float*)d_in[10];
  const float* Wloc   = (const float*)d_in[11];
  const float* vvec   = (const float*)d_in[12];

  float* ctx  = (float*)d_out;             // [B,E]
  float* wout = (float*)d_out + NB * NE;   // [B,T]

  char* ws = (char*)d_ws;
  float*  qproj    = (float*)(ws + WS_QPROJ);
  float*  energies = (float*)(ws + WS_ENERG);
  ushort* wkhi     = (ushort*)(ws + WS_WKHI);
  ushort* wklo     = (ushort*)(ws + WS_WKLO);
  ushort* wlhi     = (ushort*)(ws + WS_WLHI);
  ushort* wllo     = (ushort*)(ws + WS_WLLO);
  float*  partial  = (float*)(ws + WS_PART);

  kprep<<<dim3(17 + NB), dim3(256), 0, stream>>>(Wk, Wloc, query, Wq,
                                                 wkhi, wklo, wlhi, wllo, qproj);
  ke<<<dim3(NB, NT / 128), dim3(256), 0, stream>>>(
      key, aw, conv_w, bn_g, bn_b, bn_m, bn_v,
      wkhi, wklo, wlhi, wllo, vvec, qproj, energies);
  ks<<<dim3(NB), dim3(256), 0, stream>>>(energies, mask, wout);
  kc1<<<dim3(NB, 16), dim3(256), 0, stream>>>(key, wout, partial);
  kc2<<<dim3(NB), dim3(512), 0, stream>>>(partial, ctx);
}

// Round 9
// 291.839 us; speedup vs baseline: 1.3984x; 1.0157x over previous
//
#include <hip/hip_runtime.h>
#include <hip/hip_bf16.h>
#include <math.h>

#define NB 64
#define NT 1024
#define NE 512
#define NR 1024
#define NA 128
#define NF 32
#define NK 31
#define CPAD 15
#define BN_EPS 1e-5f

typedef __attribute__((ext_vector_type(4))) float f32x4;
typedef __attribute__((ext_vector_type(16))) float f32x16;
typedef __attribute__((ext_vector_type(8))) short bf16x8;
typedef __attribute__((ext_vector_type(8))) unsigned short ushort8v;

// ws byte offsets
#define WS_QPROJ 0               // 64*128 f32   = 32768
#define WS_ENERG 32768           // 64*1024 f32  = 262144
#define WS_WKHI  294912          // 65536 bf16   = 131072 (32x32x16 B-frag order)
#define WS_WKLO  425984          // 131072
#define WS_WLHI  557056          // 4096 bf16    = 8192 (B-frag order)
#define WS_WLLO  565248          // 8192
#define WS_PART  573440          // 64*16*512 f32 = 2097152

__device__ __forceinline__ ushort f2bf(float x) {
  union { __hip_bfloat16 h; ushort u; } v;
  v.h = __float2bfloat16(x);   // native cast (RTNE); compiler pairs into cvt_pk
  return v.u;
}
__device__ __forceinline__ float bf2f(ushort h) {
  union { unsigned u; float f; } v; v.u = ((unsigned)h) << 16; return v.f;
}
__device__ __forceinline__ float tanh_fast(float x) {
  float ax = fminf(fabsf(x), 15.f);
  float e = __expf(2.f * ax);
  float r = (e - 1.f) / (e + 1.f);
  return copysignf(r, x);
}

#define FENCE() asm volatile("" ::: "memory")
#define WAIT_LGKM0() asm volatile("s_waitcnt lgkmcnt(0)" ::: "memory")

// ---- prep: Wk/Wloc -> bf16 hi/lo 32x32x16 B-fragments; qproj = query@Wq ----
// frag elem g: j=g&7, l=(g>>3)&63, n=(g>>9)&3, kk=g>>11
//   value = W[kk*16 + (l>>5)*8 + j][n*32 + (l&31)]
__global__ __launch_bounds__(256) void kprep(
    const float* __restrict__ Wk, const float* __restrict__ Wloc,
    const float* __restrict__ query, const float* __restrict__ Wq,
    ushort* __restrict__ wkhi, ushort* __restrict__ wklo,
    ushort* __restrict__ wlhi, ushort* __restrict__ wllo,
    float* __restrict__ qproj) {
  __shared__ float qs[NR];
  __shared__ float part[128];
  const int blk = blockIdx.x;
  const int tid = threadIdx.x;
  if (blk < 16) {               // Wk fragments
#pragma unroll
    for (int it = 0; it < 16; ++it) {
      int g = blk * 4096 + it * 256 + tid;
      int j = g & 7, l = (g >> 3) & 63, n = (g >> 9) & 3, kk = g >> 11;
      int k = kk * 16 + (l >> 5) * 8 + j;
      int a = n * 32 + (l & 31);
      float val = Wk[k * NA + a];
      ushort hi = f2bf(val);
      wkhi[g] = hi;
      wklo[g] = f2bf(val - bf2f(hi));
    }
  } else if (blk == 16) {       // Wloc fragments (2 kk-steps, k=f)
#pragma unroll
    for (int it = 0; it < 16; ++it) {
      int g = it * 256 + tid;   // < 4096
      int j = g & 7, l = (g >> 3) & 63, n = (g >> 9) & 3, kk = g >> 11;
      int f = kk * 16 + (l >> 5) * 8 + j;
      int a = n * 32 + (l & 31);
      float val = Wloc[f * NA + a];
      ushort hi = f2bf(val);
      wlhi[g] = hi;
      wllo[g] = f2bf(val - bf2f(hi));
    }
  } else {                      // qproj for b = blk-17
    const int b = blk - 17;
    for (int i = tid; i < NR; i += 256) qs[i] = query[b * NR + i];
    __syncthreads();
    int a = tid & 127, h = tid >> 7;
    float acc = 0.f;
#pragma unroll 8
    for (int r = h * 512; r < h * 512 + 512; ++r) acc += qs[r] * Wq[r * NA + a];
    if (h) part[a] = acc;
    __syncthreads();
    if (!h) qproj[b * NA + a] = acc + part[a];
  }
}

// ---- ke helpers ----
__device__ __forceinline__ void issue_kr(const float* kbase, int ec, int tid,
                                         f32x4 kr[8]) {
#pragma unroll
  for (int i = 0; i < 8; ++i) {
    int fi = i * 256 + tid;
    int row = fi >> 4, c4 = fi & 15;
    kr[i] = *(const f32x4*)(kbase + (size_t)row * NE + ec * 64 + c4 * 4);
  }
}

__device__ __forceinline__ void cw_tile(const f32x4 kr[8], int tid,
                                        ushort* khi, ushort* klo) {
#pragma unroll
  for (int i = 0; i < 8; ++i) {
    int fi = i * 256 + tid;
    int row = fi >> 4, c4 = fi & 15;
    f32x4 v4 = kr[i];
    ushort4 h4, lo4;
    h4.x = f2bf(v4.x); lo4.x = f2bf(v4.x - bf2f(h4.x));
    h4.y = f2bf(v4.y); lo4.y = f2bf(v4.y - bf2f(h4.y));
    h4.z = f2bf(v4.z); lo4.z = f2bf(v4.z - bf2f(h4.z));
    h4.w = f2bf(v4.w); lo4.w = f2bf(v4.w - bf2f(h4.w));
    int byteoff = (row * 128 + c4 * 8) ^ ((row & 7) << 4);
    *(ushort4*)((char*)khi + byteoff) = h4;
    *(ushort4*)((char*)klo + byteoff) = lo4;
  }
}

// async copy 4KB of B-fragments for this wave into LDS (linear layout)
__device__ __forceinline__ void stage_B(const ushort* src_base, ushort* lds_base,
                                        int wv, int lane) {
#pragma unroll
  for (int p = 0; p < 4; ++p) {
    const ushort* g = src_base + wv * 2048 + p * 512 + lane * 8;
    ushort* d = lds_base + wv * 2048 + p * 512;
    __builtin_amdgcn_global_load_lds(
        (const __attribute__((address_space(1))) unsigned int*)g,
        (__attribute__((address_space(3))) unsigned int*)d, 16, 0, 0);
  }
}

// ---- energies[b,t] = tanh(q + key@Wk + featsT@Wloc) . v  (32x32x16 MFMA) ----
__global__ __launch_bounds__(256, 2) void ke(
    const float* __restrict__ key, const float* __restrict__ aw,
    const float* __restrict__ conv_w, const float* __restrict__ bn_g,
    const float* __restrict__ bn_b, const float* __restrict__ bn_m,
    const float* __restrict__ bn_v,
    const ushort* __restrict__ wkhi, const ushort* __restrict__ wklo,
    const ushort* __restrict__ wlhi, const ushort* __restrict__ wllo,
    const float* __restrict__ vvec, const float* __restrict__ qproj,
    float* __restrict__ energies) {
  __shared__ ushort khi[128 * 64];   // key tile [row][k] bf16, byte ^= (row&7)<<4; reused featsT
  __shared__ ushort klo[128 * 64];
  __shared__ ushort bhl[8192];       // Wk chunk hi, frag order [kk4][n4][l64][j8]
  __shared__ ushort bll[8192];       // lo
  __shared__ float x_lds[2][160];    // conv input slice (158 used)
  __shared__ float cw[NF * 2 * NK];  // conv weights
  __shared__ float q_lds[NA], v_lds[NA];

  const int b = blockIdx.x;
  const int t0 = blockIdx.y * 128;
  const int tid = threadIdx.x;
  const int l = tid & 63;
  const int w = tid >> 6;            // wave: rows [t0+w*32, +32)

  for (int i = tid; i < 2 * 158; i += 256) {
    int c = i / 158, p = i - c * 158;
    int t = t0 - CPAD + p;
    x_lds[c][p] = (t >= 0 && t < NT) ? aw[b * 2 * NT + c * NT + t] : 0.f;
  }
  for (int i = tid; i < NF * 2 * NK; i += 256) cw[i] = conv_w[i];
  if (tid < NA) {
    q_lds[tid] = qproj[b * NA + tid];
    v_lds[tid] = vvec[tid];
  }

  f32x16 acc[4];
#pragma unroll
  for (int n = 0; n < 4; ++n)
#pragma unroll
    for (int r = 0; r < 16; ++r) acc[n][r] = 0.f;

  const float* kbase = key + (size_t)b * NT * NE + (size_t)t0 * NE;

  __syncthreads();   // drains all prior vmem (vmcnt=0 from here; manual counts valid)

  // ---- pipelined staging: tile 0 ----
  f32x4 kr[8];
  issue_kr(kbase, 0, tid, kr);               // K0 (8 loads)
  stage_B(wkhi + 0, bhl, w, l);              // G0 (8 gll)
  stage_B(wklo + 0, bll, w, l);
  FENCE();                                   // pin FIFO: loads below cannot hoist above G0
  cw_tile(kr, tid, khi, klo);                // waits K0 only (compiler-counted)
  issue_kr(kbase, 1, tid, kr);               // K1 in flight
  asm volatile("s_waitcnt vmcnt(8)" ::: "memory");   // drain G0, keep K1
  WAIT_LGKM0();
  __builtin_amdgcn_s_barrier();
  FENCE();

  for (int ec = 0; ec < 8; ++ec) {
    // ---- MFMA phase on tile ec (kr for tile ec+1 in flight) ----
#pragma unroll
    for (int kk = 0; kk < 4; ++kk) {
      int row = w * 32 + (l & 31);
      int abyte = (row * 128 + kk * 32 + ((l >> 5) * 16)) ^ ((l & 7) << 4);
      bf16x8 ahi = *(bf16x8*)((char*)khi + abyte);
      bf16x8 alo = *(bf16x8*)((char*)klo + abyte);
#pragma unroll
      for (int n = 0; n < 4; ++n) {
        bf16x8 bh = *(bf16x8*)(bhl + ((kk * 4 + n) * 64 + l) * 8);
        bf16x8 bl = *(bf16x8*)(bll + ((kk * 4 + n) * 64 + l) * 8);
        acc[n] = __builtin_amdgcn_mfma_f32_32x32x16_bf16(ahi, bh, acc[n], 0, 0, 0);
        acc[n] = __builtin_amdgcn_mfma_f32_32x32x16_bf16(ahi, bl, acc[n], 0, 0, 0);
        acc[n] = __builtin_amdgcn_mfma_f32_32x32x16_bf16(alo, bh, acc[n], 0, 0, 0);
      }
    }
    WAIT_LGKM0();
    __builtin_amdgcn_s_barrier();            // all waves done reading tile ec
    FENCE();
    if (ec < 7) {
      stage_B(wkhi + (ec + 1) * 8192, bhl, w, l);   // G(ec+1): 8 gll
      stage_B(wklo + (ec + 1) * 8192, bll, w, l);
      FENCE();                               // pin FIFO: kr loads stay younger than glls
      cw_tile(kr, tid, khi, klo);            // convert tile ec+1 (waits kr)
      if (ec < 6) {
        issue_kr(kbase, ec + 2, tid, kr);    // tile ec+2 in flight
        asm volatile("s_waitcnt vmcnt(8)" ::: "memory");  // drain G(ec+1), keep kr
      } else {
        asm volatile("s_waitcnt vmcnt(0)" ::: "memory");
      }
      WAIT_LGKM0();
      __builtin_amdgcn_s_barrier();          // tile ec+1 ready
      FENCE();
    }
  }

  // ---- loc term: featsT[t][f] (A, 2 k-steps) @ Wloc frags (B) ----
  FENCE();
  {
    const ushort8v* sh = (const ushort8v*)wlhi;
    const ushort8v* sl = (const ushort8v*)wllo;
#pragma unroll
    for (int i = 0; i < 2; ++i) {
      int idx = i * 256 + tid;       // 512 vecs
      ((ushort8v*)bhl)[idx] = sh[idx];
      ((ushort8v*)bll)[idx] = sl[idx];
    }
  }
  {
    int t = tid & 127, fg = tid >> 7;   // 16 f per thread
    ushort8v fh[2], fl[2];
#pragma unroll
    for (int ff = 0; ff < 16; ++ff) {
      int f = fg * 16 + ff;
      float s = 0.f;
#pragma unroll
      for (int c = 0; c < 2; ++c)
#pragma unroll
        for (int k = 0; k < NK; ++k)
          s += cw[(f * 2 + c) * NK + k] * x_lds[c][t + k];
      s = fmaxf(s, 0.f);
      float scale = rsqrtf(bn_v[f] + BN_EPS) * bn_g[f];
      float bias = bn_b[f] - bn_m[f] * scale;
      s = s * scale + bias;
      ushort hi = f2bf(s);
      ((ushort*)fh)[ff] = hi;
      ((ushort*)fl)[ff] = f2bf(s - bf2f(hi));
    }
    // featsT row t: 32 f, stride 64B; two 16B blocks, byte ^= (t&7)<<4
    int base0 = (t * 64 + fg * 32) ^ ((t & 7) << 4);
    int base1 = (t * 64 + fg * 32 + 16) ^ ((t & 7) << 4);
    *(ushort8v*)((char*)khi + base0) = fh[0];
    *(ushort8v*)((char*)khi + base1) = fh[1];
    *(ushort8v*)((char*)klo + base0) = fl[0];
    *(ushort8v*)((char*)klo + base1) = fl[1];
  }
  __syncthreads();
#pragma unroll
  for (int kk = 0; kk < 2; ++kk) {
    int row = w * 32 + (l & 31);
    int abyte = ((row * 64 + kk * 32 + ((l >> 5) * 16))) ^ ((row & 7) << 4);
    bf16x8 ahi = *(bf16x8*)((char*)khi + abyte);
    bf16x8 alo = *(bf16x8*)((char*)klo + abyte);
#pragma unroll
    for (int n = 0; n < 4; ++n) {
      bf16x8 bh = *(bf16x8*)(bhl + ((kk * 4 + n) * 64 + l) * 8);
      bf16x8 bl = *(bf16x8*)(bll + ((kk * 4 + n) * 64 + l) * 8);
      acc[n] = __builtin_amdgcn_mfma_f32_32x32x16_bf16(ahi, bh, acc[n], 0, 0, 0);
      acc[n] = __builtin_amdgcn_mfma_f32_32x32x16_bf16(ahi, bl, acc[n], 0, 0, 0);
      acc[n] = __builtin_amdgcn_mfma_f32_32x32x16_bf16(alo, bh, acc[n], 0, 0, 0);
    }
  }

  // ---- epilogue: energies = sum_a tanh(acc + q[a]) * v[a] ----
  // D: col a = n*32 + (l&31), row t = w*32 + 4*(l>>5) + (r&3) + 8*(r>>2)
  float er[16];
#pragma unroll
  for (int r = 0; r < 16; ++r) er[r] = 0.f;
#pragma unroll
  for (int n = 0; n < 4; ++n) {
    int a = n * 32 + (l & 31);
    float qa = q_lds[a], va = v_lds[a];
#pragma unroll
    for (int r = 0; r < 16; ++r) er[r] += tanh_fast(acc[n][r] + qa) * va;
  }
#pragma unroll
  for (int r = 0; r < 16; ++r) {
    float s = er[r];
    s += __shfl_xor(s, 1, 64);
    s += __shfl_xor(s, 2, 64);
    s += __shfl_xor(s, 4, 64);
    s += __shfl_xor(s, 8, 64);
    s += __shfl_xor(s, 16, 64);
    if ((l & 31) == 0)
      energies[b * NT + t0 + w * 32 + 4 * (l >> 5) + (r & 3) + 8 * (r >> 2)] = s;
  }
}

// ---- context phase 1 (fused masked-softmax): partials over 64-t chunks ----
__global__ __launch_bounds__(256) void kc1(
    const float* __restrict__ energies, const int* __restrict__ mask,
    const float* __restrict__ key, float* __restrict__ wout,
    float* __restrict__ part) {
  __shared__ float w_lds[NT];        // exp(e - mx), unnormalized
  __shared__ float redm[4], reds[4];
  __shared__ f32x4 red[128];
  int b = blockIdx.x, tc = blockIdx.y;   // grid (64, 16)
  int tid = threadIdx.x;

  // masked softmax over T (recomputed per tc-block; 8KB L2-hot reads)
  float vals[4];
  float mx = -INFINITY;
#pragma unroll
  for (int j = 0; j < 4; ++j) {
    int t = tid + j * 256;
    float e = energies[b * NT + t];
    if (mask[b * NT + t] != 0) e = -INFINITY;
    vals[j] = e;
    mx = fmaxf(mx, e);
  }
#pragma unroll
  for (int m = 1; m < 64; m <<= 1) mx = fmaxf(mx, __shfl_xor(mx, m, 64));
  if ((tid & 63) == 0) redm[tid >> 6] = mx;
  __syncthreads();
  mx = fmaxf(fmaxf(redm[0], redm[1]), fmaxf(redm[2], redm[3]));
  float s = 0.f;
#pragma unroll
  for (int j = 0; j < 4; ++j) {
    float p = expf(vals[j] - mx);
    w_lds[tid + j * 256] = p;
    s += p;
  }
#pragma unroll
  for (int m = 1; m < 64; m <<= 1) s += __shfl_xor(s, m, 64);
  if ((tid & 63) == 0) reds[tid >> 6] = s;
  __syncthreads();
  s = reds[0] + reds[1] + reds[2] + reds[3];
  float inv = 1.f / s;

  // ctx partial over rows tc*64 .. +64 (coalesced f32x4 streaming)
  int e4 = (tid & 127) * 4, th = tid >> 7;
  const float* kp = key + (size_t)b * NT * NE + (size_t)(tc * 64 + th * 32) * NE + e4;
  f32x4 acc = (f32x4){0.f, 0.f, 0.f, 0.f};
#pragma unroll 8
  for (int t = 0; t < 32; ++t) {
    float wv = w_lds[tc * 64 + th * 32 + t];
    f32x4 k4 = *(const f32x4*)(kp + (size_t)t * NE);
    acc += wv * k4;
  }
  if (th) red[tid & 127] = acc;
  __syncthreads();
  if (!th) {
    acc += red[tid];
    acc *= inv;
    *(f32x4*)&part[((size_t)(b * 16 + tc)) * NE + e4] = acc;
  }

  // weights output (once per b)
  if (tc == 0) {
#pragma unroll
    for (int j = 0; j < 4; ++j)
      wout[b * NT + tid + j * 256] = w_lds[tid + j * 256] * inv;
  }
}

// ---------------- context: phase 2 reduce ----------------
__global__ __launch_bounds__(512) void kc2(const float* __restrict__ part,
                                           float* __restrict__ ctx) {
  int b = blockIdx.x, e = threadIdx.x;
  float s = 0.f;
#pragma unroll
  for (int tc = 0; tc < 16; ++tc) s += part[(b * 16 + tc) * NE + e];
  ctx[b * NE + e] = s;
}

extern "C" void kernel_launch(void* const* d_in, const int* in_sizes, int n_in,
                              void* d_out, int out_size, void* d_ws, size_t ws_size,
                              hipStream_t stream) {
  const float* query  = (const float*)d_in[0];
  const float* key    = (const float*)d_in[1];
  const float* aw     = (const float*)d_in[2];
  const int*   mask   = (const int*)d_in[3];
  const float* Wq     = (const float*)d_in[4];
  const float* Wk     = (const float*)d_in[5];
  const float* conv_w = (const float*)d_in[6];
  const float* bn_g   = (const float*)d_in[7];
  const float* bn_b   = (const float*)d_in[8];
  const float* bn_m   = (const float*)d_in[9];
  const float* bn_v   = (const float*)d_in[10];
  const float* Wloc   = (const float*)d_in[11];
  const float* vvec   = (const float*)d_in[12];

  float* ctx  = (float*)d_out;             // [B,E]
  float* wout = (float*)d_out + NB * NE;   // [B,T]

  char* ws = (char*)d_ws;
  float*  qproj    = (float*)(ws + WS_QPROJ);
  float*  energies = (float*)(ws + WS_ENERG);
  ushort* wkhi     = (ushort*)(ws + WS_WKHI);
  ushort* wklo     = (ushort*)(ws + WS_WKLO);
  ushort* wlhi     = (ushort*)(ws + WS_WLHI);
  ushort* wllo     = (ushort*)(ws + WS_WLLO);
  float*  partial  = (float*)(ws + WS_PART);

  kprep<<<dim3(17 + NB), dim3(256), 0, stream>>>(Wk, Wloc, query, Wq,
                                                 wkhi, wklo, wlhi, wllo, qproj);
  ke<<<dim3(NB, NT / 128), dim3(256), 0, stream>>>(
      key, aw, conv_w, bn_g, bn_b, bn_m, bn_v,
      wkhi, wklo, wlhi, wllo, vvec, qproj, energies);
  kc1<<<dim3(NB, 16), dim3(256), 0, stream>>>(energies, mask, key, wout, partial);
  kc2<<<dim3(NB), dim3(512), 0, stream>>>(partial, ctx);
}